// Round 1
// baseline (684.053 us; speedup 1.0000x reference)
//
#include <hip/hip_runtime.h>
#include <hip/hip_bf16.h>
#include <stdint.h>

typedef __bf16 bf16_t;
typedef __bf16 bf16x8 __attribute__((ext_vector_type(8)));
typedef float floatx4 __attribute__((ext_vector_type(4)));

#define B_ 32
#define HP 58
#define WP 66

// ws layout (bytes)
#define XPAD_OFF   0u
#define WAGG_OFF   62717952u     // 32*58*66*256*2
#define POOLED_OFF 100466688u    // + 32*9*256*256*2
#define ATTN_OFF   100499456u
#define BIASAGG_OFF 100499968u

__device__ __forceinline__ void async_copy16(const void* gsrc, void* ldst) {
  __builtin_amdgcn_global_load_lds(
      (const __attribute__((address_space(1))) unsigned int*)gsrc,
      (__attribute__((address_space(3))) unsigned int*)ldst, 16, 0, 0);
}

// ---------------- kernel 1: pad + convert + GAP partial sums ----------------
__global__ void pad_pool(const float* __restrict__ x, bf16_t* __restrict__ xpad,
                         float* __restrict__ pooled) {
  const int hp = blockIdx.x;   // 0..57
  const int b  = blockIdx.y;
  const int c  = threadIdx.x;  // 0..255
  const int h  = hp - 1;
  const bool hvalid = (h >= 0) && (h < 56);
  bf16_t* dst = xpad + ((size_t)(b * 58 + hp)) * (66 * 256);
  const float* srcrow = x + ((size_t)(b * 56 + (hvalid ? h : 0))) * (56 * 256);
  float sum = 0.f;
  for (int wp = 0; wp < 66; ++wp) {
    int w = wp - 1;
    float v = 0.f;
    if (hvalid && w >= 0 && w < 56) { v = srcrow[w * 256 + c]; sum += v; }
    dst[wp * 256 + c] = (bf16_t)v;
  }
  if (hvalid) atomicAdd(&pooled[b * 256 + c], sum);
}

// ---------------- kernel 2: router MLP + softmax + bias agg ----------------
__global__ void router(const float* __restrict__ pooled, const float* __restrict__ w1,
                       const float* __restrict__ b1, const float* __restrict__ w2,
                       const float* __restrict__ b2, const float* __restrict__ biases,
                       float* __restrict__ attn, float* __restrict__ biasagg) {
  __shared__ float ps[8192];
  __shared__ float hs[2048];
  __shared__ float lg[128];
  __shared__ float at[128];
  const int t = threadIdx.x;
  for (int i = t; i < 8192; i += 256) ps[i] = pooled[i] * (1.0f / 3136.0f);
  __syncthreads();
  for (int task = t; task < 2048; task += 256) {
    int b = task >> 6, j = task & 63;
    float s = b1[j];
    const float* pb = ps + b * 256;
    for (int c = 0; c < 256; ++c) s += pb[c] * w1[c * 64 + j];
    hs[task] = fmaxf(s, 0.f);
  }
  __syncthreads();
  if (t < 128) {
    int b = t >> 2, k = t & 3;
    float s = b2[k];
    const float* hb = hs + b * 64;
    for (int j = 0; j < 64; ++j) s += hb[j] * w2[j * 4 + k];
    lg[t] = s * (1.0f / 30.0f);
  }
  __syncthreads();
  if (t < 32) {
    int b = t;
    float z0 = lg[b*4], z1 = lg[b*4+1], z2 = lg[b*4+2], z3 = lg[b*4+3];
    float m = fmaxf(fmaxf(z0, z1), fmaxf(z2, z3));
    float e0 = expf(z0-m), e1 = expf(z1-m), e2 = expf(z2-m), e3 = expf(z3-m);
    float inv = 1.0f / (e0 + e1 + e2 + e3);
    at[b*4] = e0*inv; at[b*4+1] = e1*inv; at[b*4+2] = e2*inv; at[b*4+3] = e3*inv;
    attn[b*4] = at[b*4]; attn[b*4+1] = at[b*4+1];
    attn[b*4+2] = at[b*4+2]; attn[b*4+3] = at[b*4+3];
  }
  __syncthreads();
  for (int i = t; i < 8192; i += 256) {
    int b = i >> 8, f = i & 255;
    biasagg[i] = at[b*4]*biases[f] + at[b*4+1]*biases[256+f]
               + at[b*4+2]*biases[512+f] + at[b*4+3]*biases[768+f];
  }
}

// ---------------- kernel 3: weight aggregation + transpose to [b][tap][f][c] ----------------
__global__ void wagg_kernel(const float* __restrict__ kers, const float* __restrict__ attn,
                            bf16_t* __restrict__ wagg) {
  const int b = blockIdx.x, tap = blockIdx.y;
  const int t = threadIdx.x;
  __shared__ bf16_t tile[32][258];  // +2 pad: conflict-free transpose
  float a0 = attn[b*4], a1 = attn[b*4+1], a2 = attn[b*4+2], a3 = attn[b*4+3];
  const float* k0 = kers + ((size_t)(0 * 9 + tap)) * 65536;
  const float* k1 = kers + ((size_t)(1 * 9 + tap)) * 65536;
  const float* k2 = kers + ((size_t)(2 * 9 + tap)) * 65536;
  const float* k3 = kers + ((size_t)(3 * 9 + tap)) * 65536;
  bf16_t* wt = wagg + ((size_t)(b * 9 + tap)) * 65536;
  const int fr = t >> 4, li = t & 15;
  for (int cc0 = 0; cc0 < 256; cc0 += 32) {
    __syncthreads();
    for (int cl = 0; cl < 32; ++cl) {
      int o = (cc0 + cl) * 256 + t;
      float s = a0 * k0[o] + a1 * k1[o] + a2 * k2[o] + a3 * k3[o];
      tile[cl][t] = (bf16_t)s;
    }
    __syncthreads();
    for (int it = 0; it < 16; ++it) {
      int f = it * 16 + fr;
      union { __bf16 h[2]; unsigned u; } pk;
      pk.h[0] = tile[li * 2][f];
      pk.h[1] = tile[li * 2 + 1][f];
      *(unsigned*)((char*)(wt + f * 256 + cc0) + li * 4) = pk.u;
    }
  }
}

// ---------------- kernel 4: implicit-GEMM conv with per-sample weights ----------------
// tile: 8h x 14w (M=112) x 256f; 4 waves of 112x64; K = 4 cq * 9 tap * 2 ks * 32
#define PBUF_BYTES 20480   // 160 pos * 8 granules * 16B
#define BBUF_BYTES 16384   // 256 f * 4 granules * 16B

__global__ __launch_bounds__(256, 2)
void conv_mfma(const bf16_t* __restrict__ xpad, const bf16_t* __restrict__ wagg,
               const float* __restrict__ biasagg, float* __restrict__ out) {
  __shared__ char lds[2 * PBUF_BYTES + 2 * BBUF_BYTES];  // 73728 B
  char* ldsP = lds;
  char* ldsB = lds + 2 * PBUF_BYTES;

  const int tile = blockIdx.x;  // 0..27  (b-major grid: all tiles of a b adjacent)
  const int b    = blockIdx.y;
  const int h0 = (tile >> 2) * 8;
  const int w0 = (tile & 3) * 14;

  const int tid  = threadIdx.x;
  const int lane = tid & 63;
  const int wv   = tid >> 6;
  const int l15  = lane & 15;
  const int quad = lane >> 4;
  const int n0   = wv * 64;

  const char* xb = (const char*)xpad + (size_t)b * (HP * WP * 256 * 2);
  const char* wb = (const char*)wagg + (size_t)b * (9 * 256 * 256 * 2);

  // static per-lane offsets
  int offs[7];
#pragma unroll
  for (int mi = 0; mi < 7; ++mi) {
    int m = mi * 16 + l15;
    int ty = m / 14;
    int tx = m - ty * 14;
    offs[mi] = ty * 16 + tx;   // patch position index
  }
  int boff[4];
#pragma unroll
  for (int ni = 0; ni < 4; ++ni) {
    int f = n0 + ni * 16 + l15;
    boff[ni] = f * 64 + ((quad ^ ((f >> 1) & 3)) << 4);  // swizzled granule
  }

  floatx4 acc[7][4];
#pragma unroll
  for (int mi = 0; mi < 7; ++mi)
#pragma unroll
    for (int ni = 0; ni < 4; ++ni) acc[mi][ni] = (floatx4){0.f, 0.f, 0.f, 0.f};

  auto stage_patch = [&](int cq, int pb) {
#pragma unroll
    for (int ii = 0; ii < 5; ++ii) {
      int i20 = wv * 5 + ii;            // 0..19, wave-uniform
      int p = i20 * 8 + (lane >> 3);    // patch position 0..159
      int gsrc = (lane & 7) ^ (p & 7);  // XOR swizzle
      const char* src = xb + ((size_t)((h0 + (p >> 4)) * WP + (w0 + (p & 15))) * 512)
                           + cq * 128 + gsrc * 16;
      async_copy16(src, ldsP + pb * PBUF_BYTES + i20 * 1024);
    }
  };
  auto stage_b = [&](int cq, int tap, int ks, int bb) {
    const char* wt = wb + (size_t)tap * (256 * 256 * 2);
    int kbyte = cq * 128 + ks * 64;
#pragma unroll
    for (int ii = 0; ii < 4; ++ii) {
      int i16 = wv * 4 + ii;            // 0..15, wave-uniform
      int f = i16 * 16 + (lane >> 2);
      int gsrc = (lane & 3) ^ ((f >> 1) & 3);
      const char* src = wt + f * 512 + kbyte + gsrc * 16;
      async_copy16(src, ldsB + bb * BBUF_BYTES + i16 * 1024);
    }
  };

  stage_patch(0, 0);
  stage_b(0, 0, 0, 0);
  __syncthreads();

  int step = 0, cq = 0, tap = 0, ks = 0;
  while (true) {
    int nks = ks + 1, ntap = tap, ncq = cq;
    if (nks == 2) { nks = 0; ++ntap; if (ntap == 9) { ntap = 0; ++ncq; } }
    const bool have_next = (ncq < 4);
    if (have_next) {
      stage_b(ncq, ntap, nks, (step + 1) & 1);
      if (ncq != cq) stage_patch(ncq, ncq & 1);
    }
    {
      const char* pc = ldsP + (cq & 1) * PBUF_BYTES;
      const char* bc = ldsB + (step & 1) * BBUF_BYTES;
      const int tapoff = (tap / 3) * 16 + (tap % 3);
      const int gA = ks * 4 + quad;
      bf16x8 a[7];
#pragma unroll
      for (int mi = 0; mi < 7; ++mi) {
        int p = offs[mi] + tapoff;
        int addr = (p << 7) + ((gA ^ (p & 7)) << 4);
        a[mi] = *(const bf16x8*)(pc + addr);
      }
      bf16x8 bv[4];
#pragma unroll
      for (int ni = 0; ni < 4; ++ni) bv[ni] = *(const bf16x8*)(bc + boff[ni]);
#pragma unroll
      for (int mi = 0; mi < 7; ++mi)
#pragma unroll
        for (int ni = 0; ni < 4; ++ni)
          acc[mi][ni] = __builtin_amdgcn_mfma_f32_16x16x32_bf16(a[mi], bv[ni], acc[mi][ni], 0, 0, 0);
    }
    __syncthreads();
    if (!have_next) break;
    cq = ncq; tap = ntap; ks = nks; ++step;
  }

  // epilogue: D layout col=lane&15 (f), row=quad*4+reg (m)
  float bias[4];
#pragma unroll
  for (int ni = 0; ni < 4; ++ni) bias[ni] = biasagg[b * 256 + n0 + ni * 16 + l15];
  float* outb = out + (size_t)b * (56 * 56 * 256);
#pragma unroll
  for (int mi = 0; mi < 7; ++mi) {
#pragma unroll
    for (int rg = 0; rg < 4; ++rg) {
      int m = mi * 16 + quad * 4 + rg;
      int ty = m / 14, tx = m - ty * 14;
      float* orow = outb + ((size_t)((h0 + ty) * 56) + (w0 + tx)) * 256 + n0 + l15;
#pragma unroll
      for (int ni = 0; ni < 4; ++ni) orow[ni * 16] = acc[mi][ni][rg] + bias[ni];
    }
  }
}

extern "C" void kernel_launch(void* const* d_in, const int* in_sizes, int n_in,
                              void* d_out, int out_size, void* d_ws, size_t ws_size,
                              hipStream_t stream) {
  const float* x      = (const float*)d_in[0];
  const float* kers   = (const float*)d_in[1];
  const float* biases = (const float*)d_in[2];
  const float* w1     = (const float*)d_in[3];
  const float* b1     = (const float*)d_in[4];
  const float* w2     = (const float*)d_in[5];
  const float* b2     = (const float*)d_in[6];
  float* outp = (float*)d_out;
  char* ws = (char*)d_ws;

  bf16_t* xpad   = (bf16_t*)(ws + XPAD_OFF);
  bf16_t* wagg   = (bf16_t*)(ws + WAGG_OFF);
  float* pooled  = (float*)(ws + POOLED_OFF);
  float* attn    = (float*)(ws + ATTN_OFF);
  float* biasagg = (float*)(ws + BIASAGG_OFF);

  hipMemsetAsync(pooled, 0, 32 * 256 * sizeof(float), stream);
  pad_pool<<<dim3(58, 32), 256, 0, stream>>>(x, xpad, pooled);
  router<<<1, 256, 0, stream>>>(pooled, w1, b1, w2, b2, biases, attn, biasagg);
  wagg_kernel<<<dim3(32, 9), 256, 0, stream>>>(kers, attn, wagg);
  conv_mfma<<<dim3(28, 32), 256, 0, stream>>>(xpad, wagg, biasagg, outp);
}

// Round 2
// 389.021 us; speedup vs baseline: 1.7584x; 1.7584x over previous
//
#include <hip/hip_runtime.h>
#include <hip/hip_bf16.h>
#include <stdint.h>

typedef __bf16 bf16_t;
typedef __bf16 bf16x4 __attribute__((ext_vector_type(4)));
typedef __bf16 bf16x8 __attribute__((ext_vector_type(8)));
typedef float floatx4 __attribute__((ext_vector_type(4)));

#define B_ 32
#define HP 58
#define WP 66

// ws layout (bytes)
#define XPAD_OFF   0u
#define WAGG_OFF   62717952u     // 32*58*66*256*2
#define POOLED_OFF 100466688u    // + 32*9*256*256*2
#define ATTN_OFF   100499456u
#define BIASAGG_OFF 100499968u

__device__ __forceinline__ void async_copy16(const void* gsrc, void* ldst) {
  __builtin_amdgcn_global_load_lds(
      (const __attribute__((address_space(1))) unsigned int*)gsrc,
      (__attribute__((address_space(3))) unsigned int*)ldst, 16, 0, 0);
}

// ---------------- kernel 1: pad + convert + GAP partial sums ----------------
__global__ void pad_pool(const float* __restrict__ x, bf16_t* __restrict__ xpad,
                         float* __restrict__ pooled) {
  const int hp = blockIdx.x;   // 0..57
  const int b  = blockIdx.y;
  const int c  = threadIdx.x;  // 0..255
  const int h  = hp - 1;
  const bool hvalid = (h >= 0) && (h < 56);
  bf16_t* dst = xpad + ((size_t)(b * 58 + hp)) * (66 * 256);
  const float* srcrow = x + ((size_t)(b * 56 + (hvalid ? h : 0))) * (56 * 256);
  float sum = 0.f;
  for (int wp = 0; wp < 66; ++wp) {
    int w = wp - 1;
    float v = 0.f;
    if (hvalid && w >= 0 && w < 56) { v = srcrow[w * 256 + c]; sum += v; }
    dst[wp * 256 + c] = (bf16_t)v;
  }
  if (hvalid) atomicAdd(&pooled[b * 256 + c], sum);
}

// ---------------- kernel 2: router MLP + softmax + bias agg ----------------
__global__ void router(const float* __restrict__ pooled, const float* __restrict__ w1,
                       const float* __restrict__ b1, const float* __restrict__ w2,
                       const float* __restrict__ b2, const float* __restrict__ biases,
                       float* __restrict__ attn, float* __restrict__ biasagg) {
  __shared__ float ps[8192];
  __shared__ float hs[2048];
  __shared__ float lg[128];
  __shared__ float at[128];
  const int t = threadIdx.x;
  for (int i = t; i < 8192; i += 256) ps[i] = pooled[i] * (1.0f / 3136.0f);
  __syncthreads();
  for (int task = t; task < 2048; task += 256) {
    int b = task >> 6, j = task & 63;
    float s = b1[j];
    const float* pb = ps + b * 256;
    for (int c = 0; c < 256; ++c) s += pb[c] * w1[c * 64 + j];
    hs[task] = fmaxf(s, 0.f);
  }
  __syncthreads();
  if (t < 128) {
    int b = t >> 2, k = t & 3;
    float s = b2[k];
    const float* hb = hs + b * 64;
    for (int j = 0; j < 64; ++j) s += hb[j] * w2[j * 4 + k];
    lg[t] = s * (1.0f / 30.0f);
  }
  __syncthreads();
  if (t < 32) {
    int b = t;
    float z0 = lg[b*4], z1 = lg[b*4+1], z2 = lg[b*4+2], z3 = lg[b*4+3];
    float m = fmaxf(fmaxf(z0, z1), fmaxf(z2, z3));
    float e0 = expf(z0-m), e1 = expf(z1-m), e2 = expf(z2-m), e3 = expf(z3-m);
    float inv = 1.0f / (e0 + e1 + e2 + e3);
    at[b*4] = e0*inv; at[b*4+1] = e1*inv; at[b*4+2] = e2*inv; at[b*4+3] = e3*inv;
    attn[b*4] = at[b*4]; attn[b*4+1] = at[b*4+1];
    attn[b*4+2] = at[b*4+2]; attn[b*4+3] = at[b*4+3];
  }
  __syncthreads();
  for (int i = t; i < 8192; i += 256) {
    int b = i >> 8, f = i & 255;
    biasagg[i] = at[b*4]*biases[f] + at[b*4+1]*biases[256+f]
               + at[b*4+2]*biases[512+f] + at[b*4+3]*biases[768+f];
  }
}

// ---------------- kernel 3: weight aggregation + transpose to [b][tap][f][c] ----------------
// v2: grid (cq=4, tap=9, b=32) = 1152 blocks for occupancy; float4 global loads;
// LDS tile [c_local=64][260] (row 520 B): fill = conflict-free b64 writes,
// readout = 8x strided b16 reads (<=4-way) + 16B coalesced global store.
__global__ __launch_bounds__(256)
void wagg_kernel(const float* __restrict__ kers, const float* __restrict__ attn,
                 bf16_t* __restrict__ wagg) {
  const int cq  = blockIdx.x;  // 0..3  (c quarter)
  const int tap = blockIdx.y;  // 0..8
  const int b   = blockIdx.z;  // 0..31
  const int t   = threadIdx.x;
  __shared__ bf16_t tile[64 * 260];

  const float a0 = attn[b*4+0], a1 = attn[b*4+1], a2 = attn[b*4+2], a3 = attn[b*4+3];
  const float* k0 = kers + ((size_t)(0 * 9 + tap)) * 65536;
  const float* k1 = kers + ((size_t)(1 * 9 + tap)) * 65536;
  const float* k2 = kers + ((size_t)(2 * 9 + tap)) * 65536;
  const float* k3 = kers + ((size_t)(3 * 9 + tap)) * 65536;

  const int fq = t & 63;       // f group: f0 = fq*4
  const int cl = t >> 6;       // 0..3
  const int f0 = fq * 4;
#pragma unroll
  for (int pass = 0; pass < 16; ++pass) {
    const int c_local = pass * 4 + cl;           // 0..63
    const size_t o = (size_t)(cq * 64 + c_local) * 256 + f0;
    floatx4 v0 = *(const floatx4*)(k0 + o);
    floatx4 v1 = *(const floatx4*)(k1 + o);
    floatx4 v2 = *(const floatx4*)(k2 + o);
    floatx4 v3 = *(const floatx4*)(k3 + o);
    bf16x4 r;
#pragma unroll
    for (int j = 0; j < 4; ++j)
      r[j] = (bf16_t)(a0 * v0[j] + a1 * v1[j] + a2 * v2[j] + a3 * v3[j]);
    *(bf16x4*)&tile[c_local * 260 + f0] = r;     // 8B write, 8-aligned (520B rows)
  }
  __syncthreads();

  bf16_t* wt = wagg + ((size_t)(b * 9 + tap)) * 65536 + cq * 64;
#pragma unroll
  for (int pass = 0; pass < 8; ++pass) {
    const int gi = pass * 256 + t;               // 0..2047
    const int f  = gi >> 3;                      // 0..255
    const int cg = gi & 7;                       // 0..7  (8-c granule)
    bf16x8 v;
#pragma unroll
    for (int i = 0; i < 8; ++i) v[i] = tile[(cg * 8 + i) * 260 + f];
    *(bf16x8*)(wt + (size_t)f * 256 + cg * 8) = v;  // 16B store, 16-aligned
  }
}

// ---------------- kernel 4: implicit-GEMM conv with per-sample weights ----------------
// tile: 8h x 14w (M=112) x 256f; 4 waves of 112x64; K = 4 cq * 9 tap * 2 ks * 32
#define PBUF_BYTES 20480   // 160 pos * 8 granules * 16B
#define BBUF_BYTES 16384   // 256 f * 4 granules * 16B

__global__ __launch_bounds__(256, 2)
void conv_mfma(const bf16_t* __restrict__ xpad, const bf16_t* __restrict__ wagg,
               const float* __restrict__ biasagg, float* __restrict__ out) {
  __shared__ char lds[2 * PBUF_BYTES + 2 * BBUF_BYTES];  // 73728 B
  char* ldsP = lds;
  char* ldsB = lds + 2 * PBUF_BYTES;

  const int tile = blockIdx.x;  // 0..27  (b-major grid: all tiles of a b adjacent)
  const int b    = blockIdx.y;
  const int h0 = (tile >> 2) * 8;
  const int w0 = (tile & 3) * 14;

  const int tid  = threadIdx.x;
  const int lane = tid & 63;
  const int wv   = tid >> 6;
  const int l15  = lane & 15;
  const int quad = lane >> 4;
  const int n0   = wv * 64;

  const char* xb = (const char*)xpad + (size_t)b * (HP * WP * 256 * 2);
  const char* wb = (const char*)wagg + (size_t)b * (9 * 256 * 256 * 2);

  // static per-lane offsets
  int offs[7];
#pragma unroll
  for (int mi = 0; mi < 7; ++mi) {
    int m = mi * 16 + l15;
    int ty = m / 14;
    int tx = m - ty * 14;
    offs[mi] = ty * 16 + tx;   // patch position index
  }
  int boff[4];
#pragma unroll
  for (int ni = 0; ni < 4; ++ni) {
    int f = n0 + ni * 16 + l15;
    boff[ni] = f * 64 + ((quad ^ ((f >> 1) & 3)) << 4);  // swizzled granule
  }

  floatx4 acc[7][4];
#pragma unroll
  for (int mi = 0; mi < 7; ++mi)
#pragma unroll
    for (int ni = 0; ni < 4; ++ni) acc[mi][ni] = (floatx4){0.f, 0.f, 0.f, 0.f};

  auto stage_patch = [&](int cq, int pb) {
#pragma unroll
    for (int ii = 0; ii < 5; ++ii) {
      int i20 = wv * 5 + ii;            // 0..19, wave-uniform
      int p = i20 * 8 + (lane >> 3);    // patch position 0..159
      int gsrc = (lane & 7) ^ (p & 7);  // XOR swizzle
      const char* src = xb + ((size_t)((h0 + (p >> 4)) * WP + (w0 + (p & 15))) * 512)
                           + cq * 128 + gsrc * 16;
      async_copy16(src, ldsP + pb * PBUF_BYTES + i20 * 1024);
    }
  };
  auto stage_b = [&](int cq, int tap, int ks, int bb) {
    const char* wt = wb + (size_t)tap * (256 * 256 * 2);
    int kbyte = cq * 128 + ks * 64;
#pragma unroll
    for (int ii = 0; ii < 4; ++ii) {
      int i16 = wv * 4 + ii;            // 0..15, wave-uniform
      int f = i16 * 16 + (lane >> 2);
      int gsrc = (lane & 3) ^ ((f >> 1) & 3);
      const char* src = wt + f * 512 + kbyte + gsrc * 16;
      async_copy16(src, ldsB + bb * BBUF_BYTES + i16 * 1024);
    }
  };

  stage_patch(0, 0);
  stage_b(0, 0, 0, 0);
  __syncthreads();

  int step = 0, cq = 0, tap = 0, ks = 0;
  while (true) {
    int nks = ks + 1, ntap = tap, ncq = cq;
    if (nks == 2) { nks = 0; ++ntap; if (ntap == 9) { ntap = 0; ++ncq; } }
    const bool have_next = (ncq < 4);
    if (have_next) {
      stage_b(ncq, ntap, nks, (step + 1) & 1);
      if (ncq != cq) stage_patch(ncq, ncq & 1);
    }
    {
      const char* pc = ldsP + (cq & 1) * PBUF_BYTES;
      const char* bc = ldsB + (step & 1) * BBUF_BYTES;
      const int tapoff = (tap / 3) * 16 + (tap % 3);
      const int gA = ks * 4 + quad;
      bf16x8 a[7];
#pragma unroll
      for (int mi = 0; mi < 7; ++mi) {
        int p = offs[mi] + tapoff;
        int addr = (p << 7) + ((gA ^ (p & 7)) << 4);
        a[mi] = *(const bf16x8*)(pc + addr);
      }
      bf16x8 bv[4];
#pragma unroll
      for (int ni = 0; ni < 4; ++ni) bv[ni] = *(const bf16x8*)(bc + boff[ni]);
#pragma unroll
      for (int mi = 0; mi < 7; ++mi)
#pragma unroll
        for (int ni = 0; ni < 4; ++ni)
          acc[mi][ni] = __builtin_amdgcn_mfma_f32_16x16x32_bf16(a[mi], bv[ni], acc[mi][ni], 0, 0, 0);
    }
    __syncthreads();
    if (!have_next) break;
    cq = ncq; tap = ntap; ks = nks; ++step;
  }

  // epilogue: D layout col=lane&15 (f), row=quad*4+reg (m)
  float bias[4];
#pragma unroll
  for (int ni = 0; ni < 4; ++ni) bias[ni] = biasagg[b * 256 + n0 + ni * 16 + l15];
  float* outb = out + (size_t)b * (56 * 56 * 256);
#pragma unroll
  for (int mi = 0; mi < 7; ++mi) {
#pragma unroll
    for (int rg = 0; rg < 4; ++rg) {
      int m = mi * 16 + quad * 4 + rg;
      int ty = m / 14, tx = m - ty * 14;
      float* orow = outb + ((size_t)((h0 + ty) * 56) + (w0 + tx)) * 256 + n0 + l15;
#pragma unroll
      for (int ni = 0; ni < 4; ++ni) orow[ni * 16] = acc[mi][ni][rg] + bias[ni];
    }
  }
}

extern "C" void kernel_launch(void* const* d_in, const int* in_sizes, int n_in,
                              void* d_out, int out_size, void* d_ws, size_t ws_size,
                              hipStream_t stream) {
  const float* x      = (const float*)d_in[0];
  const float* kers   = (const float*)d_in[1];
  const float* biases = (const float*)d_in[2];
  const float* w1     = (const float*)d_in[3];
  const float* b1     = (const float*)d_in[4];
  const float* w2     = (const float*)d_in[5];
  const float* b2     = (const float*)d_in[6];
  float* outp = (float*)d_out;
  char* ws = (char*)d_ws;

  bf16_t* xpad   = (bf16_t*)(ws + XPAD_OFF);
  bf16_t* wagg   = (bf16_t*)(ws + WAGG_OFF);
  float* pooled  = (float*)(ws + POOLED_OFF);
  float* attn    = (float*)(ws + ATTN_OFF);
  float* biasagg = (float*)(ws + BIASAGG_OFF);

  hipMemsetAsync(pooled, 0, 32 * 256 * sizeof(float), stream);
  pad_pool<<<dim3(58, 32), 256, 0, stream>>>(x, xpad, pooled);
  router<<<1, 256, 0, stream>>>(pooled, w1, b1, w2, b2, biases, attn, biasagg);
  wagg_kernel<<<dim3(4, 9, 32), 256, 0, stream>>>(kers, attn, wagg);
  conv_mfma<<<dim3(28, 32), 256, 0, stream>>>(xpad, wagg, biasagg, outp);
}